// Round 2
// baseline (5088.618 us; speedup 1.0000x reference)
//
#include <hip/hip_runtime.h>
#include <hip/hip_fp16.h>

#define C2X 2.8853900817779268f   // 2*log2(e)
#define LOG2E 1.4426950408889634f

// ---------------- workspace layout (bytes) ----------------
#define WYS_OFF   0u          // half [32][256][256]  WY pre-scaled by 2log2e
#define PR_OFF    4194304u    // half [32][256][256]  P_r = prem @ w_r
#define PREMH_OFF 8388608u    // half [32][256][256]  premise fp16
#define HWH_OFF   12582912u   // f32  [128][32][256]  (h@w_h)*2log2e
#define WTH_OFF   16777216u   // half [256][256]      w_t
#define WTR_OFF   16908288u   // half [256][256]      W_tr = w_t @ w_r
#define SG_OFF    17039360u   // f32 [32][256] s exchange
#define TG_OFF    17072128u   // f32 [32][256] z exchange
#define RG_OFF    17104896u   // f32 [2][32][256] r double buffer
#define CTR_OFF   17170432u   // u32 [32] barrier counters
// total ~16.4 MB

// ---------------- LDS layout (bytes) ----------------
#define PRC_OFF   0u        // [256][32] half  P_r chunk
#define WTRC_OFF  16384u    // [256][32] half  W_tr chunk
#define PREMC_OFF 32768u    // [256][32] half  prem chunk
#define WTC_OFF   49152u    // [256][32] half  w_t chunk
#define WYC_OFF   65536u    // [32 rows][520B] half, padded rows
#define HWHC_OFF  82176u    // [128][32] f32
#define SL_OFF    98560u    // 256 f32 s
#define WA_OFF    99584u    // 256 f32 w_alpha
#define AL_OFF    100608u   // 256 f32 alpha
#define R1_OFF    101632u   // 256 f32 r_{t-1}/r_{t-2}
#define ZL_OFF    102656u   // 256 f32 z
#define PART_OFF  103680u   // [8][32] f32
#define RED_OFF   104704u   // 16 f32
#define LDS_TOTAL 104768u

// ---------------- prep: GEMMs ----------------
// MODE 0: WY rows (b,l) -> half(acc*C2X)
// MODE 1: HWh rows (t,b) -> f32(acc*C2X)
// MODE 2: generic rows (W_tr: x=w_t) -> half(acc)
// MODE 3: P_r rows (b,l) -> half(acc)
template<int MODE>
__global__ __launch_bounds__(256) void prep_gemm(const float* __restrict__ x,
                                                 const float* __restrict__ w,
                                                 float* __restrict__ outf,
                                                 __half* __restrict__ outh) {
    __shared__ float At[8][256];
    const int d = threadIdx.x;
    const int row0 = blockIdx.x * 8;
    for (int rr = 0; rr < 8; ++rr) {
        int r = row0 + rr;
        const float* src;
        if (MODE == 0 || MODE == 3) { int b = r >> 8, l = r & 255; src = x + (size_t)(b * 384 + l) * 256; }
        else if (MODE == 1)         { int t = r >> 5, bb = r & 31; src = x + (size_t)(bb * 384 + 256 + t) * 256; }
        else                        { src = x + (size_t)r * 256; }
        At[rr][d] = src[d];
    }
    __syncthreads();
    float acc[8] = {0.f,0.f,0.f,0.f,0.f,0.f,0.f,0.f};
    for (int k = 0; k < 256; k += 4) {
        float w0 = w[(size_t)(k + 0) * 256 + d];
        float w1 = w[(size_t)(k + 1) * 256 + d];
        float w2 = w[(size_t)(k + 2) * 256 + d];
        float w3 = w[(size_t)(k + 3) * 256 + d];
#pragma unroll
        for (int rr = 0; rr < 8; ++rr) {
            const float4 a = *(const float4*)&At[rr][k];
            float t0 = fmaf(a.x, w0, acc[rr]);
            t0 = fmaf(a.y, w1, t0);
            t0 = fmaf(a.z, w2, t0);
            acc[rr] = fmaf(a.w, w3, t0);
        }
    }
    for (int rr = 0; rr < 8; ++rr) {
        int r = row0 + rr;
        if (MODE == 0)      outh[(size_t)r * 256 + d] = __float2half(acc[rr] * C2X);
        else if (MODE == 1) outf[(size_t)r * 256 + d] = acc[rr] * C2X;
        else                outh[(size_t)r * 256 + d] = __float2half(acc[rr]);
    }
}

// ---------------- prep: fp16 conversions ----------------
__global__ __launch_bounds__(256) void prep_cvt(const float* __restrict__ x,
                                                const float* __restrict__ wt,
                                                __half* __restrict__ prem_h,
                                                __half* __restrict__ wt_h) {
    int i = blockIdx.x * 256 + threadIdx.x;
    float4 v; __half* dst; int e;
    if (i < 524288) {
        e = i * 4; int b = e >> 16;
        v = *(const float4*)(x + (size_t)e + (size_t)b * 32768);
        dst = prem_h + e;
    } else if (i < 540672) {
        e = (i - 524288) * 4;
        v = *(const float4*)(wt + e);
        dst = wt_h + e;
    } else return;
    __half h[4] = {__float2half(v.x),__float2half(v.y),__float2half(v.z),__float2half(v.w)};
    *(uint2*)dst = *(const uint2*)h;
}

// ---------------- cross-block helpers ----------------
__device__ __forceinline__ void gstore(float* p, float v) {
    __hip_atomic_store(p, v, __ATOMIC_RELAXED, __HIP_MEMORY_SCOPE_AGENT);
}
__device__ __forceinline__ float gload(const float* p) {
    return __hip_atomic_load(p, __ATOMIC_RELAXED, __HIP_MEMORY_SCOPE_AGENT);
}
__device__ __forceinline__ void sync8(unsigned* c, unsigned target) {
    __syncthreads();   // all waves' prior stores retired (vmcnt(0) before s_barrier)
    if (threadIdx.x == 0) {
        __hip_atomic_fetch_add(c, 1u, __ATOMIC_RELEASE, __HIP_MEMORY_SCOPE_AGENT);
        while (__hip_atomic_load(c, __ATOMIC_RELAXED, __HIP_MEMORY_SCOPE_AGENT) < target)
            __builtin_amdgcn_s_sleep(1);
        (void)__hip_atomic_load(c, __ATOMIC_ACQUIRE, __HIP_MEMORY_SCOPE_AGENT);
    }
    __syncthreads();
}
__device__ __forceinline__ float blk_reduce16(float v, float* part, int tid) {
    v += __shfl_xor(v, 32, 64);                 // combine g-pair within wave
    if ((tid & 32) == 0) part[((tid >> 6) << 5) + (tid & 31)] = v;
    __syncthreads();
    float r = 0.f;
    if (tid < 32) {
#pragma unroll
        for (int ww = 0; ww < 8; ++ww) r += part[(ww << 5) + tid];
    }
    return r;
}

// ---------------- main: 8 blocks per batch, IF$-barrier recurrence ----------------
__global__ __launch_bounds__(512, 1) void wbw_main(
    const __half* __restrict__ wys, const __half* __restrict__ prh,
    const __half* __restrict__ premh, const __half* __restrict__ wth,
    const __half* __restrict__ wtrh, const float* __restrict__ hwh,
    const float* __restrict__ walpha, float* __restrict__ out,
    float* __restrict__ sg, float* __restrict__ tg, float* __restrict__ rg,
    unsigned* __restrict__ ctr)
{
    extern __shared__ char lds[];
    const int tid = threadIdx.x;
    const int b = blockIdx.x >> 3, j = blockIdx.x & 7;
    const int lane32 = tid & 31;
    const int g = tid >> 5;   // 0..15

    __half* prc    = (__half*)(lds + PRC_OFF);
    __half* wtrc   = (__half*)(lds + WTRC_OFF);
    __half* premc  = (__half*)(lds + PREMC_OFF);
    __half* wtc    = (__half*)(lds + WTC_OFF);
    float*  hwhc   = (float*)(lds + HWHC_OFF);
    float*  s_lds  = (float*)(lds + SL_OFF);
    float*  wa_lds = (float*)(lds + WA_OFF);
    float*  al_lds = (float*)(lds + AL_OFF);
    float*  r1_lds = (float*)(lds + R1_OFF);
    float*  z_lds  = (float*)(lds + ZL_OFF);
    float*  part   = (float*)(lds + PART_OFF);
    float*  red    = (float*)(lds + RED_OFF);
    unsigned* ctrb = ctr + b;

    // ---- stage the four [256][32] fp16 chunk matrices ----
    {
        int row = tid >> 1, c0 = (tid & 1) << 4;          // 16 halves each
        size_t goff = (size_t)row * 256 + j * 32 + c0;
        unsigned lo = (unsigned)row * 64 + (unsigned)c0 * 2;
        const uint4* s0 = (const uint4*)(prh  + (size_t)b * 65536 + goff);
        const uint4* s1 = (const uint4*)(wtrh + goff);
        const uint4* s2 = (const uint4*)(premh + (size_t)b * 65536 + goff);
        const uint4* s3 = (const uint4*)(wth  + goff);
        *(uint4*)(lds + PRC_OFF   + lo) = s0[0]; *(uint4*)(lds + PRC_OFF   + lo + 16) = s0[1];
        *(uint4*)(lds + WTRC_OFF  + lo) = s1[0]; *(uint4*)(lds + WTRC_OFF  + lo + 16) = s1[1];
        *(uint4*)(lds + PREMC_OFF + lo) = s2[0]; *(uint4*)(lds + PREMC_OFF + lo + 16) = s2[1];
        *(uint4*)(lds + WTC_OFF   + lo) = s3[0]; *(uint4*)(lds + WTC_OFF   + lo + 16) = s3[1];
    }
    // ---- stage WY l-chunk, padded rows (520B) ----
    {
        int row = tid >> 4, s16 = tid & 15;               // 16 halves each
        const uint2* src = (const uint2*)(wys + ((size_t)(b * 256 + j * 32 + row)) * 256 + s16 * 16);
        uint2* dst = (uint2*)(lds + WYC_OFF + (unsigned)row * 520 + (unsigned)s16 * 32);
        dst[0] = src[0]; dst[1] = src[1]; dst[2] = src[2]; dst[3] = src[3];
    }
    // ---- stage hwh [128][32] ----
    for (int it = 0; it < 8; ++it) {
        int idx = it * 512 + tid;
        int tt = idx >> 5, dL = idx & 31;
        hwhc[idx] = hwh[((size_t)tt * 32 + b) * 256 + j * 32 + dL];
    }
    if (tid < 256) {
        wa_lds[tid] = walpha[tid];
        al_lds[tid] = 0.f;
        r1_lds[tid] = 0.f;
    }
    __syncthreads();

    unsigned seq = 0;
    for (int t = 0; t < 128; ++t) {
        // ---- P1: s_t[d-chunk] = hwh + C2X*( alpha_{t-1}@P_r + r_{t-2}@W_tr ) ----
        float acc = 0.f;
#pragma unroll
        for (int i = 0; i < 16; ++i) {
            int l = g + (i << 4);
            float av = al_lds[l], rv = r1_lds[l];
            acc = fmaf(av, __half2float(prc[(l << 5) + lane32]), acc);
            acc = fmaf(rv, __half2float(wtrc[(l << 5) + lane32]), acc);
        }
        {
            float sred = blk_reduce16(acc, part, tid);
            if (tid < 32) {
                float sval = fmaf(sred, C2X, hwhc[t * 32 + tid]);
                gstore(&sg[b * 256 + j * 32 + tid], sval);
            }
        }
        sync8(ctrb, 8u * (++seq));

        // ---- gather s; issue r_{t-1} load into regs (consumed later) ----
        float rv_reg = 0.f;
        if (tid < 256) {
            s_lds[tid] = gload(&sg[b * 256 + tid]);
            rv_reg = gload(&rg[((t + 1) & 1) * 8192 + b * 256 + tid]);   // r_{t-1}
        }
        __syncthreads();

        // ---- P2: z[l-chunk] = -2 * sum_d wa[d]/(exp2(WY'+s')+1) ----
        {
            const __half* wyrow = (const __half*)(lds + WYC_OFF + (unsigned)lane32 * 520);
            float za = 0.f;
#pragma unroll
            for (int i = 0; i < 16; ++i) {
                int d = g + (i << 4);
                float arg = __half2float(wyrow[d]) + s_lds[d];
                float u = __builtin_amdgcn_rcpf(__builtin_amdgcn_exp2f(arg) + 1.f);
                za = fmaf(wa_lds[d], u, za);
            }
            float zred = blk_reduce16(za, part, tid);
            if (tid < 32) gstore(&tg[b * 256 + j * 32 + tid], -2.f * zred);
        }
        if (tid < 256) r1_lds[tid] = rv_reg;   // publish r_{t-1} to LDS (visible after sync8)
        sync8(ctrb, 8u * (++seq));

        // ---- gather z ----
        if (tid < 256) z_lds[tid] = gload(&tg[b * 256 + tid]);
        __syncthreads();

        // ---- P3: redundant softmax over 256 ----
        float zz = -1e30f, ee = 0.f;
        if (tid < 256) zz = z_lds[tid];
        {
            float mv = zz;
#pragma unroll
            for (int off = 32; off; off >>= 1) mv = fmaxf(mv, __shfl_xor(mv, off, 64));
            if (tid < 256 && (tid & 63) == 0) red[tid >> 6] = mv;
        }
        __syncthreads();
        if (tid < 256) {
            float M = fmaxf(fmaxf(red[0], red[1]), fmaxf(red[2], red[3]));
            ee = __builtin_amdgcn_exp2f((zz - M) * LOG2E);
            float sv = ee;
#pragma unroll
            for (int off = 32; off; off >>= 1) sv += __shfl_xor(sv, off, 64);
            if ((tid & 63) == 0) red[4 + (tid >> 6)] = sv;
        }
        __syncthreads();
        if (tid < 256) {
            float denom = red[4] + red[5] + red[6] + red[7];
            al_lds[tid] = ee * __builtin_amdgcn_rcpf(denom);
        }
        __syncthreads();

        // ---- P4: r_t[d-chunk] = alpha@prem + r_{t-1}@w_t ----
        float rc = 0.f;
#pragma unroll
        for (int i = 0; i < 16; ++i) {
            int l = g + (i << 4);
            float av = al_lds[l], rv = r1_lds[l];
            rc = fmaf(av, __half2float(premc[(l << 5) + lane32]), rc);
            rc = fmaf(rv, __half2float(wtc[(l << 5) + lane32]), rc);
        }
        {
            float rred = blk_reduce16(rc, part, tid);
            if (tid < 32) {
                gstore(&rg[(t & 1) * 8192 + b * 256 + j * 32 + tid], rred);
                out[((size_t)b * 128 + t) * 256 + j * 32 + tid] = rred;
            }
        }
        __syncthreads();   // protect part[]/al_lds before next iteration
    }
}

extern "C" void kernel_launch(void* const* d_in, const int* in_sizes, int n_in,
                              void* d_out, int out_size, void* d_ws, size_t ws_size,
                              hipStream_t stream) {
    const float* x   = (const float*)d_in[0];
    const float* wy  = (const float*)d_in[1];
    const float* wh  = (const float*)d_in[2];
    const float* wr  = (const float*)d_in[3];
    const float* wal = (const float*)d_in[4];
    const float* wt  = (const float*)d_in[5];

    char* ws = (char*)d_ws;
    __half* wys    = (__half*)(ws + WYS_OFF);
    __half* prh    = (__half*)(ws + PR_OFF);
    __half* premh  = (__half*)(ws + PREMH_OFF);
    float*  hwh    = (float*)(ws + HWH_OFF);
    __half* wth    = (__half*)(ws + WTH_OFF);
    __half* wtrh   = (__half*)(ws + WTR_OFF);
    float*  sg     = (float*)(ws + SG_OFF);
    float*  tg     = (float*)(ws + TG_OFF);
    float*  rg     = (float*)(ws + RG_OFF);
    unsigned* ctr  = (unsigned*)(ws + CTR_OFF);

    hipFuncSetAttribute((const void*)wbw_main,
                        hipFuncAttributeMaxDynamicSharedMemorySize, (int)LDS_TOTAL);

    prep_gemm<0><<<1024, 256, 0, stream>>>(x,  wy, nullptr, wys);
    prep_gemm<1><<<512,  256, 0, stream>>>(x,  wh, hwh, nullptr);
    prep_gemm<3><<<1024, 256, 0, stream>>>(x,  wr, nullptr, prh);
    prep_gemm<2><<<32,   256, 0, stream>>>(wt, wr, nullptr, wtrh);
    prep_cvt<<<2112, 256, 0, stream>>>(x, wt, premh, wth);
    hipMemsetAsync(ws + RG_OFF, 0, 65536 + 128, stream);

    wbw_main<<<256, 512, LDS_TOTAL, stream>>>(wys, prh, premh, wth, wtrh, hwh,
                                              wal, (float*)d_out, sg, tg, rg, ctr);
}

// Round 3
// 820.460 us; speedup vs baseline: 6.2022x; 6.2022x over previous
//
#include <hip/hip_runtime.h>
#include <hip/hip_fp16.h>

#define C2X 2.8853900817779268f   // 2*log2(e)
#define LOG2E 1.4426950408889634f

// ---------------- workspace layout (bytes) ----------------
#define WYS_OFF   0u          // half [32][256][256]  WY pre-scaled by 2log2e
#define PR_OFF    4194304u    // half [32][256][256]  P_r = prem @ w_r
#define PREMH_OFF 8388608u    // half [32][256][256]  premise fp16
#define HWH_OFF   12582912u   // f32  [128][32][256]  (h@w_h)*2log2e
#define WTH_OFF   16777216u   // half [256][256]      w_t
#define WTR_OFF   16908288u   // half [256][256]      W_tr = w_t @ w_r
#define ZP_OFF    17039360u   // f32 [4][32][8][256]  z-partial slots (1 MB)
#define RCH_OFF   18087936u   // f32 [4][32][256]     r-chunk slots (128 KB)
#define FLG_OFF   18219008u   // u32 [4][32][8][16]   flags, 64B-padded (64 KB)

// ---------------- LDS layout (bytes) ----------------
#define PRC_OFF   0u        // [256][32] half  P_r chunk
#define WTRC_OFF  16384u    // [256][32] half  W_tr chunk
#define PREMC_OFF 32768u    // [256][32] half  prem chunk
#define WTC_OFF   49152u    // [256][32] half  w_t chunk
#define WYC_OFF   65536u    // [256][32] half  WY chunk (prescaled)
#define HWHC_OFF  81920u    // [128][32] f32
#define SCH_OFF   98304u    // 32 f32  s chunk (prescaled)
#define WACH_OFF  98432u    // 32 f32  w_alpha chunk
#define AL_OFF    98560u    // 256 f32 alpha
#define RB0_OFF   99584u    // 256 f32 r buffer 0
#define RB1_OFF   100608u   // 256 f32 r buffer 1
#define ZPL_OFF   101632u   // 256 f32 local z-partial staging
#define PART_OFF  102656u   // [16][32] f32
#define RED_OFF   104704u   // 16 f32
#define LDS_TOTAL 104768u

// ---------------- prep: GEMMs ----------------
// MODE 0: WY rows (b,l) -> half(acc*C2X)
// MODE 1: HWh rows (t,b) -> f32(acc*C2X)
// MODE 2: generic rows (W_tr: x=w_t) -> half(acc)
// MODE 3: P_r rows (b,l) -> half(acc)
template<int MODE>
__global__ __launch_bounds__(256) void prep_gemm(const float* __restrict__ x,
                                                 const float* __restrict__ w,
                                                 float* __restrict__ outf,
                                                 __half* __restrict__ outh) {
    __shared__ float At[8][256];
    const int d = threadIdx.x;
    const int row0 = blockIdx.x * 8;
    for (int rr = 0; rr < 8; ++rr) {
        int r = row0 + rr;
        const float* src;
        if (MODE == 0 || MODE == 3) { int b = r >> 8, l = r & 255; src = x + (size_t)(b * 384 + l) * 256; }
        else if (MODE == 1)         { int t = r >> 5, bb = r & 31; src = x + (size_t)(bb * 384 + 256 + t) * 256; }
        else                        { src = x + (size_t)r * 256; }
        At[rr][d] = src[d];
    }
    __syncthreads();
    float acc[8] = {0.f,0.f,0.f,0.f,0.f,0.f,0.f,0.f};
    for (int k = 0; k < 256; k += 4) {
        float w0 = w[(size_t)(k + 0) * 256 + d];
        float w1 = w[(size_t)(k + 1) * 256 + d];
        float w2 = w[(size_t)(k + 2) * 256 + d];
        float w3 = w[(size_t)(k + 3) * 256 + d];
#pragma unroll
        for (int rr = 0; rr < 8; ++rr) {
            const float4 a = *(const float4*)&At[rr][k];
            float t0 = fmaf(a.x, w0, acc[rr]);
            t0 = fmaf(a.y, w1, t0);
            t0 = fmaf(a.z, w2, t0);
            acc[rr] = fmaf(a.w, w3, t0);
        }
    }
    for (int rr = 0; rr < 8; ++rr) {
        int r = row0 + rr;
        if (MODE == 0)      outh[(size_t)r * 256 + d] = __float2half(acc[rr] * C2X);
        else if (MODE == 1) outf[(size_t)r * 256 + d] = acc[rr] * C2X;
        else                outh[(size_t)r * 256 + d] = __float2half(acc[rr]);
    }
}

__global__ __launch_bounds__(256) void prep_cvt(const float* __restrict__ x,
                                                const float* __restrict__ wt,
                                                __half* __restrict__ prem_h,
                                                __half* __restrict__ wt_h) {
    int i = blockIdx.x * 256 + threadIdx.x;
    float4 v; __half* dst; int e;
    if (i < 524288) {
        e = i * 4; int b = e >> 16;
        v = *(const float4*)(x + (size_t)e + (size_t)b * 32768);
        dst = prem_h + e;
    } else if (i < 540672) {
        e = (i - 524288) * 4;
        v = *(const float4*)(wt + e);
        dst = wt_h + e;
    } else return;
    __half h[4] = {__float2half(v.x),__float2half(v.y),__float2half(v.z),__float2half(v.w)};
    *(uint2*)dst = *(const uint2*)h;
}

// ---------------- agent-scope helpers ----------------
__device__ __forceinline__ void gstore(float* p, float v) {
    __hip_atomic_store(p, v, __ATOMIC_RELAXED, __HIP_MEMORY_SCOPE_AGENT);
}
__device__ __forceinline__ float gload(const float* p) {
    return __hip_atomic_load(p, __ATOMIC_RELAXED, __HIP_MEMORY_SCOPE_AGENT);
}
__device__ __forceinline__ unsigned gloadu(const unsigned* p) {
    return __hip_atomic_load(p, __ATOMIC_RELAXED, __HIP_MEMORY_SCOPE_AGENT);
}

// ---------------- main: 8 blocks/batch, single flag-exchange per step ----------------
__global__ __launch_bounds__(512, 1) void wbw_main(
    const __half* __restrict__ wys, const __half* __restrict__ prh,
    const __half* __restrict__ premh, const __half* __restrict__ wth,
    const __half* __restrict__ wtrh, const float* __restrict__ hwh,
    const float* __restrict__ walpha, float* __restrict__ out,
    float* __restrict__ zp_g, float* __restrict__ rch_g,
    unsigned* __restrict__ flg)
{
    extern __shared__ char lds[];
    const int tid = threadIdx.x;
    const int b = blockIdx.x >> 3, j = blockIdx.x & 7;

    __half* prc    = (__half*)(lds + PRC_OFF);
    __half* wtrc   = (__half*)(lds + WTRC_OFF);
    __half* premc  = (__half*)(lds + PREMC_OFF);
    __half* wtc    = (__half*)(lds + WTC_OFF);
    float*  hwhc   = (float*)(lds + HWHC_OFF);
    float*  s_ch   = (float*)(lds + SCH_OFF);
    float*  wa_ch  = (float*)(lds + WACH_OFF);
    float*  al     = (float*)(lds + AL_OFF);
    float*  rb0    = (float*)(lds + RB0_OFF);
    float*  rb1    = (float*)(lds + RB1_OFF);
    float*  zpl    = (float*)(lds + ZPL_OFF);
    float*  part   = (float*)(lds + PART_OFF);
    float*  red    = (float*)(lds + RED_OFF);

    // ---- stage the five [256][32] fp16 column-chunk matrices ----
    {
        const int prt = tid & 3;
        for (int it = 0; it < 2; ++it) {
            int row = it * 128 + (tid >> 2);
            size_t g = (size_t)row * 256 + j * 32 + prt * 8;
            unsigned lo = (unsigned)row * 64 + (unsigned)prt * 16;
            *(uint4*)(lds + PRC_OFF   + lo) = *(const uint4*)(prh   + (size_t)b * 65536 + g);
            *(uint4*)(lds + WTRC_OFF  + lo) = *(const uint4*)(wtrh  + g);
            *(uint4*)(lds + PREMC_OFF + lo) = *(const uint4*)(premh + (size_t)b * 65536 + g);
            *(uint4*)(lds + WTC_OFF   + lo) = *(const uint4*)(wth   + g);
            *(uint4*)(lds + WYC_OFF   + lo) = *(const uint4*)(wys   + (size_t)b * 65536 + g);
        }
    }
    // ---- stage hwh chunk [128][32] ----
    for (int it = 0; it < 8; ++it) {
        int idx = it * 512 + tid;
        int tt = idx >> 5, dd = idx & 31;
        hwhc[idx] = hwh[((size_t)tt * 32 + b) * 256 + j * 32 + dd];
    }
    if (tid < 32) wa_ch[tid] = walpha[j * 32 + tid];
    if (tid < 256) { al[tid] = 0.f; rb0[tid] = 0.f; rb1[tid] = 0.f; }
    __syncthreads();

    for (int t = 0; t < 128; ++t) {
        // ---- P1: s-chunk = hwh + C2X*(alpha_{t-1}@P_r + r_{t-2}@W_tr) ----
        {
            const int d = tid & 31, seg = tid >> 5;
            const __half* mat = (seg < 8) ? prc : wtrc;
            const float*  vec = (seg < 8) ? al : ((t & 1) ? rb0 : rb1);   // r_{t-2}
            const int l0 = (seg & 7) * 32;
            float acc = 0.f;
#pragma unroll
            for (int i = 0; i < 32; ++i)
                acc = fmaf(vec[l0 + i], __half2float(mat[(l0 + i) * 32 + d]), acc);
            part[seg * 32 + d] = acc;
        }
        __syncthreads();
        if (tid < 32) {
            float ssum = 0.f;
#pragma unroll
            for (int s2 = 0; s2 < 16; ++s2) ssum += part[s2 * 32 + tid];
            s_ch[tid] = fmaf(ssum, C2X, hwhc[t * 32 + tid]);
        }
        __syncthreads();

        // ---- P2: zpart[l] = sum_{d in chunk} wa_d / (exp2(WY'+s')+1), all 256 l ----
        {
            const int l = tid >> 1, dh = (tid & 1) << 4;
            union { uint4 u[2]; __half h[16]; } W;
            W.u[0] = *(const uint4*)(lds + WYC_OFF + (unsigned)l * 64 + (unsigned)dh * 2);
            W.u[1] = *(const uint4*)(lds + WYC_OFF + (unsigned)l * 64 + (unsigned)dh * 2 + 16);
            float acc = 0.f;
#pragma unroll
            for (int i = 0; i < 16; ++i) {
                float arg = __half2float(W.h[i]) + s_ch[dh + i];
                float u = __builtin_amdgcn_rcpf(__builtin_amdgcn_exp2f(arg) + 1.f);
                acc = fmaf(wa_ch[dh + i], u, acc);
            }
            acc += __shfl_xor(acc, 1, 64);
            if ((tid & 1) == 0) zpl[l] = acc;
        }
        __syncthreads();

        // ---- publish z-partials, then flag (r-chunk was stored at end of step t-1) ----
        if (tid < 256) gstore(&zp_g[(((t & 3) * 32 + b) * 8 + j) * 256 + tid], zpl[tid]);
        __syncthreads();   // vmcnt(0) drain of all waves' stores before flag
        if (tid == 0)
            __hip_atomic_store(&flg[((t & 3) * 32 + b) * 128 + j * 16],
                               (unsigned)(t + 1), __ATOMIC_RELEASE, __HIP_MEMORY_SCOPE_AGENT);

        // ---- poll all 8 flags (wave 0, one lane per flag, no RMW) ----
        if (tid < 64) {
            const unsigned* fp = flg + ((t & 3) * 32 + b) * 128 + tid * 16;
            const bool active = tid < 8;
            while (true) {
                unsigned v = active ? gloadu(fp) : 0xFFFFFFFFu;
                unsigned long long bad = __ballot(active && (v < (unsigned)(t + 1)));
                if (bad == 0ULL) break;
                __builtin_amdgcn_s_sleep(1);
            }
        }
        __syncthreads();

        // ---- assemble z (and r_{t-1}); redundant softmax ----
        float zz = -1e30f, ee = 0.f;
        if (tid < 256) {
            const float* zb = zp_g + ((t & 3) * 32 + b) * 2048;
            float zs = 0.f;
#pragma unroll
            for (int j2 = 0; j2 < 8; ++j2) zs += gload(zb + j2 * 256 + tid);
            zz = -2.f * zs;
            float* rb = (t & 1) ? rb1 : rb0;           // r_{t-1} target
            if (t > 0) rb[tid] = gload(&rch_g[((t & 3) * 32 + b) * 256 + tid]);
        }
        {
            float mv = zz;
#pragma unroll
            for (int off = 32; off; off >>= 1) mv = fmaxf(mv, __shfl_xor(mv, off, 64));
            if (tid < 256 && (tid & 63) == 0) red[tid >> 6] = mv;
        }
        __syncthreads();
        if (tid < 256) {
            float M = fmaxf(fmaxf(red[0], red[1]), fmaxf(red[2], red[3]));
            ee = __builtin_amdgcn_exp2f((zz - M) * LOG2E);
            float sv = ee;
#pragma unroll
            for (int off = 32; off; off >>= 1) sv += __shfl_xor(sv, off, 64);
            if ((tid & 63) == 0) red[4 + (tid >> 6)] = sv;
        }
        __syncthreads();
        if (tid < 256) {
            float denom = red[4] + red[5] + red[6] + red[7];
            al[tid] = ee * __builtin_amdgcn_rcpf(denom);
        }
        __syncthreads();

        // ---- P4: r_t-chunk = alpha_t@prem + r_{t-1}@w_t ----
        {
            const int d = tid & 31, seg = tid >> 5;
            const __half* mat = (seg < 8) ? premc : wtc;
            const float*  vec = (seg < 8) ? al : ((t & 1) ? rb1 : rb0);   // r_{t-1}
            const int l0 = (seg & 7) * 32;
            float acc = 0.f;
#pragma unroll
            for (int i = 0; i < 32; ++i)
                acc = fmaf(vec[l0 + i], __half2float(mat[(l0 + i) * 32 + d]), acc);
            part[seg * 32 + d] = acc;
        }
        __syncthreads();
        if (tid < 32) {
            float rv = 0.f;
#pragma unroll
            for (int s2 = 0; s2 < 16; ++s2) rv += part[s2 * 32 + tid];
            out[((size_t)b * 128 + t) * 256 + j * 32 + tid] = rv;
            gstore(&rch_g[((((t + 1) & 3) * 32 + b)) * 256 + j * 32 + tid], rv);
        }
        __syncthreads();
    }
}

extern "C" void kernel_launch(void* const* d_in, const int* in_sizes, int n_in,
                              void* d_out, int out_size, void* d_ws, size_t ws_size,
                              hipStream_t stream) {
    const float* x   = (const float*)d_in[0];
    const float* wy  = (const float*)d_in[1];
    const float* wh  = (const float*)d_in[2];
    const float* wr  = (const float*)d_in[3];
    const float* wal = (const float*)d_in[4];
    const float* wt  = (const float*)d_in[5];

    char* ws = (char*)d_ws;
    __half* wys    = (__half*)(ws + WYS_OFF);
    __half* prh    = (__half*)(ws + PR_OFF);
    __half* premh  = (__half*)(ws + PREMH_OFF);
    float*  hwh    = (float*)(ws + HWH_OFF);
    __half* wth    = (__half*)(ws + WTH_OFF);
    __half* wtrh   = (__half*)(ws + WTR_OFF);
    float*  zp_g   = (float*)(ws + ZP_OFF);
    float*  rch_g  = (float*)(ws + RCH_OFF);
    unsigned* flg  = (unsigned*)(ws + FLG_OFF);

    hipFuncSetAttribute((const void*)wbw_main,
                        hipFuncAttributeMaxDynamicSharedMemorySize, (int)LDS_TOTAL);

    prep_gemm<0><<<1024, 256, 0, stream>>>(x,  wy, nullptr, wys);
    prep_gemm<1><<<512,  256, 0, stream>>>(x,  wh, hwh, nullptr);
    prep_gemm<3><<<1024, 256, 0, stream>>>(x,  wr, nullptr, prh);
    prep_gemm<2><<<32,   256, 0, stream>>>(wt, wr, nullptr, wtrh);
    prep_cvt<<<2112, 256, 0, stream>>>(x, wt, premh, wth);
    hipMemsetAsync(ws + FLG_OFF, 0, 65536, stream);

    wbw_main<<<256, 512, LDS_TOTAL, stream>>>(wys, prh, premh, wth, wtrh, hwh,
                                              wal, (float*)d_out, zp_g, rch_g, flg);
}